// Round 12
// baseline (471.611 us; speedup 1.0000x reference)
//
#include <hip/hip_runtime.h>
#include <hip/hip_fp16.h>

#define TB 256
#define NBK 512     // bucket array capacity (actual buckets = cdiv(M,256) <= 512)
#define NBLK_P 128  // partition blocks (H-matrix rows)

typedef _Float16 f16;
typedef __attribute__((ext_vector_type(8))) _Float16 f16x8;
typedef __attribute__((ext_vector_type(4))) float f32x4;

__device__ __forceinline__ f32x4 mfma16(f16x8 a, f16x8 b, f32x4 c) {
    return __builtin_amdgcn_mfma_f32_16x16x32_f16(a, b, c, 0, 0, 0);
}

// ---------------- index-width detection (int32 vs int64 src/dst) -------------
__global__ void detect_idx_kernel(const int* __restrict__ s32, const int* __restrict__ d32,
                                  int nE, int* __restrict__ flag) {
    __shared__ int nz;
    if (threadIdx.x == 0) nz = 0;
    __syncthreads();
    int n = nE < 2048 ? nE : 2048;
    int local = 0;
    for (int i = threadIdx.x; i < n; i += blockDim.x) {
        if (s32[2 * i + 1] != 0 || d32[2 * i + 1] != 0) local = 1;
    }
    if (local) atomicOr(&nz, 1);
    __syncthreads();
    if (threadIdx.x == 0) *flag = (nz == 0) ? 1 : 0;   // 1 => indices are int64
}

__device__ __forceinline__ int load_idx(const void* p, int e, int is64) {
    return is64 ? (int)((const long long*)p)[e] : ((const int*)p)[e];
}

// ---------------- CSR build: contention-free counting sort -------------------
__global__ __launch_bounds__(TB) void passA_kernel(
        const void* __restrict__ dst, const int* __restrict__ flag,
        int* __restrict__ H, int nE, int EC, int nBk) {
    __shared__ int lh[NBK];
    for (int i = threadIdx.x; i < NBK; i += TB) lh[i] = 0;
    __syncthreads();
    const int is64 = *flag;
    const int lo = blockIdx.x * EC;
    const int hi = min(nE, lo + EC);
    for (int j = lo + threadIdx.x; j < hi; j += TB) {
        int d = load_idx(dst, j, is64);
        atomicAdd(&lh[d >> 8], 1);
    }
    __syncthreads();
    for (int i = threadIdx.x; i < nBk; i += TB) H[blockIdx.x * nBk + i] = lh[i];
}

__global__ __launch_bounds__(TB) void colscan_kernel(int* __restrict__ H,
                                                     int* __restrict__ T, int nBk) {
    int t = blockIdx.x * blockDim.x + threadIdx.x;
    if (t >= nBk) return;
    int run = 0;
    for (int b = 0; b < NBLK_P; ++b) {
        int v = H[b * nBk + t];
        H[b * nBk + t] = run;
        run += v;
    }
    T[t] = run;
}

__global__ __launch_bounds__(512) void bucket_scan_kernel(const int* __restrict__ hb,
                                                          int* __restrict__ bcur, int nBk) {
    __shared__ int sh[512];
    const int tid = threadIdx.x;
    int v = (tid < nBk) ? hb[tid] : 0;
    sh[tid] = v;
    __syncthreads();
    for (int off = 1; off < 512; off <<= 1) {
        int t = (tid >= off) ? sh[tid - off] : 0;
        __syncthreads();
        sh[tid] += t;
        __syncthreads();
    }
    if (tid < nBk) bcur[tid] = sh[tid] - v;   // exclusive
}

__global__ __launch_bounds__(TB) void passB_kernel(
        const void* __restrict__ src, const void* __restrict__ dst,
        const int* __restrict__ flag, const int* __restrict__ H,
        const int* __restrict__ Bbase, int2* __restrict__ ebuf,
        int nE, int EC, int nBk) {
    __shared__ int lbase[NBK];
    __shared__ int lcur[NBK];
    for (int i = threadIdx.x; i < nBk; i += TB) {
        lbase[i] = Bbase[i] + H[blockIdx.x * nBk + i];
        lcur[i] = 0;
    }
    __syncthreads();
    const int is64 = *flag;
    const int lo = blockIdx.x * EC;
    const int hi = min(nE, lo + EC);
    for (int j = lo + threadIdx.x; j < hi; j += TB) {
        int d = load_idx(dst, j, is64);
        int s = load_idx(src, j, is64);
        int bk = d >> 8;
        int p = lbase[bk] + atomicAdd(&lcur[bk], 1);
        ebuf[p] = make_int2(d, s);
    }
}

__global__ __launch_bounds__(TB) void bucket_build_kernel(
        const int2* __restrict__ ebuf, const int* __restrict__ Bbase,
        int* __restrict__ rowptr, int* __restrict__ col, int M, int nBk, int nE) {
    __shared__ int ldeg[256];
    __shared__ int wtot[4];
    const int bk = blockIdx.x;
    const int tid = threadIdx.x;
    const int node0 = bk << 8;
    const int lo = Bbase[bk];
    const int hi = (bk + 1 < nBk) ? Bbase[bk + 1] : nE;

    ldeg[tid] = 0;
    __syncthreads();
    for (int j = lo + tid; j < hi; j += TB)
        atomicAdd(&ldeg[ebuf[j].x & 255], 1);
    __syncthreads();

    const int lane = tid & 63, wv = tid >> 6;
    int v = ldeg[tid];
    int x = v;
    #pragma unroll
    for (int off = 1; off < 64; off <<= 1) {
        int y = __shfl_up(x, off);
        if (lane >= off) x += y;
    }
    if (lane == 63) wtot[wv] = x;
    __syncthreads();
    int wbase = 0;
    #pragma unroll
    for (int w = 0; w < 4; ++w) if (w < wv) wbase += wtot[w];
    const int excl = lo + wbase + (x - v);

    const int node = node0 + tid;
    if (node < M) rowptr[node] = excl;
    if (bk == 0 && tid == 0) rowptr[M] = nE;
    __syncthreads();
    ldeg[tid] = excl;   // becomes cursor
    __syncthreads();
    for (int j = lo + tid; j < hi; j += TB) {
        int2 e = ebuf[j];
        int pos = atomicAdd(&ldeg[e.x & 255], 1);
        col[pos] = e.y;
    }
}

// ---------------- f32 -> fp16 conversion -------------------------------------
__global__ void tofp16_kernel(const float4* __restrict__ in, uint2* __restrict__ out, int n4) {
    int t = blockIdx.x * blockDim.x + threadIdx.x;
    if (t >= n4) return;
    float4 v = in[t];
    __half2 a = __floats2half2_rn(v.x, v.y);
    __half2 b = __floats2half2_rn(v.z, v.w);
    out[t] = make_uint2(*(unsigned*)&a, *(unsigned*)&b);
}

// ---------------- fused gather (fp16 in, fp16/f32 out) -----------------------
// 4-deep load pipeline + packed-fp16 accumulation (f32 cross-slice reduce).
template<int F>
__global__ __launch_bounds__(TB) void gather_fused_h(
        const uint2* __restrict__ xh, const int* __restrict__ col,
        const int* __restrict__ rowptr, const float* __restrict__ sbuf,
        const f16* __restrict__ hcopyh, f16* __restrict__ outh,
        float* __restrict__ outf, int M, int ldout, int doRelu) {
    constexpr int C4 = F / 4;      // 8-byte chunks per row: 16 (F=64) or 8 (F=32)
    constexpr int ES = 64 / C4;    // edge slices per wave
    const int wave = threadIdx.x >> 6;
    const int lane = threadIdx.x & 63;
    const int node = blockIdx.x * (TB / 64) + wave;
    if (node >= M) return;
    const int c4 = lane & (C4 - 1);
    const int es = lane >> (F == 64 ? 4 : 3);

    const int s = rowptr[node], e = rowptr[node + 1];
    __half2 h0 = __floats2half2_rn(0.f, 0.f);
    __half2 h1 = h0;
    int j = s + es;
    // 4-deep: 4 independent index+row loads in flight per wave slice
    for (; j + 3 * ES < e; j += 4 * ES) {
        int cs0 = col[j];
        int cs1 = col[j + ES];
        int cs2 = col[j + 2 * ES];
        int cs3 = col[j + 3 * ES];
        uint2 u0 = xh[(size_t)cs0 * C4 + c4];
        uint2 u1 = xh[(size_t)cs1 * C4 + c4];
        uint2 u2 = xh[(size_t)cs2 * C4 + c4];
        uint2 u3 = xh[(size_t)cs3 * C4 + c4];
        h0 = __hadd2(h0, *(__half2*)&u0.x); h1 = __hadd2(h1, *(__half2*)&u0.y);
        h0 = __hadd2(h0, *(__half2*)&u1.x); h1 = __hadd2(h1, *(__half2*)&u1.y);
        h0 = __hadd2(h0, *(__half2*)&u2.x); h1 = __hadd2(h1, *(__half2*)&u2.y);
        h0 = __hadd2(h0, *(__half2*)&u3.x); h1 = __hadd2(h1, *(__half2*)&u3.y);
    }
    for (; j < e; j += ES) {
        int cs = col[j];
        uint2 u = xh[(size_t)cs * C4 + c4];
        h0 = __hadd2(h0, *(__half2*)&u.x);
        h1 = __hadd2(h1, *(__half2*)&u.y);
    }
    float2 f0 = __half22float2(h0);
    float2 f1 = __half22float2(h1);
    float ax = f0.x, ay = f0.y, az = f1.x, aw = f1.y;
    #pragma unroll
    for (int d = C4; d < 64; d <<= 1) {
        ax += __shfl_xor(ax, d);
        ay += __shfl_xor(ay, d);
        az += __shfl_xor(az, d);
        aw += __shfl_xor(aw, d);
    }
    if (es == 0) {
        const float inv = 1.0f / fmaxf((float)(e - s), 1.0f);
        float4 v = make_float4(ax * inv, ay * inv, az * inv, aw * inv);
        if (sbuf) {
            float4 sv = *(const float4*)(sbuf + (size_t)node * F + 4 * c4);
            v.x += sv.x; v.y += sv.y; v.z += sv.z; v.w += sv.w;
        }
        if (doRelu) {
            v.x = fmaxf(v.x, 0.f); v.y = fmaxf(v.y, 0.f);
            v.z = fmaxf(v.z, 0.f); v.w = fmaxf(v.w, 0.f);
        }
        if (outh) {
            __half2 p0 = __floats2half2_rn(v.x, v.y);
            __half2 p1 = __floats2half2_rn(v.z, v.w);
            *(uint2*)(outh + (size_t)node * ldout + 4 * c4) =
                make_uint2(*(unsigned*)&p0, *(unsigned*)&p1);
            if (hcopyh) {   // concat: copy prev h (fp16) into upper half
                uint2 hv = *(const uint2*)(hcopyh + (size_t)node * F + 4 * c4);
                *(uint2*)(outh + (size_t)node * ldout + F + 4 * c4) = hv;
            }
        }
        if (outf)
            *(float4*)(outf + (size_t)node * ldout + 4 * c4) = v;
    }
}

// ---------------- MFMA dual-OUTPUT GEMM: Yh = fp16(A@Wn); S = A@Ws + b -------
template<int K, int N>
__global__ __launch_bounds__(TB) void gemm_mfma_dualout(
        const f16* __restrict__ Ah, const float* __restrict__ Wn,
        const float* __restrict__ Ws, const float* __restrict__ bias,
        f16* __restrict__ Yh, float* __restrict__ S, int M) {
    constexpr int KP = K + 8;      // padded k-stride (halves) -> conflict-free
    constexpr int NT = N / 16;     // n tiles per wave
    constexpr int KS = K / 32;     // k steps
    __shared__ f16 lwn[N * KP];
    __shared__ f16 lws[N * KP];
    const int tid = threadIdx.x;
    for (int idx = tid; idx < K * N; idx += TB) {
        int k = idx / N, n = idx - k * N;
        lwn[n * KP + k] = (f16)Wn[idx];
        lws[n * KP + k] = (f16)Ws[idx];
    }
    __syncthreads();

    const int lane = tid & 63;
    const int lr = lane & 15, lh = lane >> 4;
    const int rbase = blockIdx.x * 128 + (tid >> 6) * 32;
    const bool v0 = rbase < M, v1 = rbase + 16 < M;   // M % 16 == 0

    f32x4 accY[2][NT], accS[2][NT];
    const f32x4 z = {0.f, 0.f, 0.f, 0.f};
    #pragma unroll
    for (int r = 0; r < 2; ++r)
        #pragma unroll
        for (int t = 0; t < NT; ++t) { accY[r][t] = z; accS[r][t] = z; }

    for (int ks = 0; ks < KS; ++ks) {
        const int kb = ks * 32 + lh * 8;
        f16x8 a0 = {}, a1 = {};
        if (v0) a0 = *(const f16x8*)(Ah + (size_t)(rbase + lr) * K + kb);
        if (v1) a1 = *(const f16x8*)(Ah + (size_t)(rbase + 16 + lr) * K + kb);
        #pragma unroll
        for (int t = 0; t < NT; ++t) {
            f16x8 bn = *(const f16x8*)(&lwn[(t * 16 + lr) * KP + kb]);
            f16x8 bs = *(const f16x8*)(&lws[(t * 16 + lr) * KP + kb]);
            if (v0) { accY[0][t] = mfma16(a0, bn, accY[0][t]);
                      accS[0][t] = mfma16(a0, bs, accS[0][t]); }
            if (v1) { accY[1][t] = mfma16(a1, bn, accY[1][t]);
                      accS[1][t] = mfma16(a1, bs, accS[1][t]); }
        }
    }

    #pragma unroll
    for (int r = 0; r < 2; ++r) {
        const bool vr = r ? v1 : v0;
        if (vr) {
            const int rT = rbase + r * 16 + 4 * lh;   // D: row=(lane>>4)*4+reg
            #pragma unroll
            for (int t = 0; t < NT; ++t) {
                const int c = t * 16 + lr;            // D: col=lane&15
                const float bb = bias[c];
                #pragma unroll
                for (int g = 0; g < 4; ++g) {
                    const int row = rT + g;
                    S[(size_t)row * N + c] = accS[r][t][g] + bb;
                    Yh[(size_t)row * N + c] = (f16)accY[r][t][g];
                }
            }
        }
    }
}

// ---------------- MFMA dual-INPUT GEMM (layer 1): relu(A@Ws + A2@Wn + b) -----
template<int K, int N>
__global__ __launch_bounds__(TB) void gemm_mfma_dualin(
        const f16* __restrict__ Ah, const f16* __restrict__ A2h,
        const float* __restrict__ Ws, const float* __restrict__ Wn,
        const float* __restrict__ bias, f16* __restrict__ outh, int M) {
    constexpr int KP = K + 8;
    constexpr int NT = N / 16;
    constexpr int KS = K / 32;
    __shared__ f16 lws[N * KP];
    __shared__ f16 lwn[N * KP];
    const int tid = threadIdx.x;
    for (int idx = tid; idx < K * N; idx += TB) {
        int k = idx / N, n = idx - k * N;
        lws[n * KP + k] = (f16)Ws[idx];
        lwn[n * KP + k] = (f16)Wn[idx];
    }
    __syncthreads();

    const int lane = tid & 63;
    const int lr = lane & 15, lh = lane >> 4;
    const int rbase = blockIdx.x * 128 + (tid >> 6) * 32;
    const bool v0 = rbase < M, v1 = rbase + 16 < M;

    f32x4 acc[2][NT];
    const f32x4 z = {0.f, 0.f, 0.f, 0.f};
    #pragma unroll
    for (int r = 0; r < 2; ++r)
        #pragma unroll
        for (int t = 0; t < NT; ++t) acc[r][t] = z;

    for (int ks = 0; ks < KS; ++ks) {
        const int kb = ks * 32 + lh * 8;
        f16x8 a0 = {}, a1 = {}, g0 = {}, g1 = {};
        if (v0) { a0 = *(const f16x8*)(Ah  + (size_t)(rbase + lr) * K + kb);
                  g0 = *(const f16x8*)(A2h + (size_t)(rbase + lr) * K + kb); }
        if (v1) { a1 = *(const f16x8*)(Ah  + (size_t)(rbase + 16 + lr) * K + kb);
                  g1 = *(const f16x8*)(A2h + (size_t)(rbase + 16 + lr) * K + kb); }
        #pragma unroll
        for (int t = 0; t < NT; ++t) {
            f16x8 bs = *(const f16x8*)(&lws[(t * 16 + lr) * KP + kb]);
            f16x8 bn = *(const f16x8*)(&lwn[(t * 16 + lr) * KP + kb]);
            if (v0) { acc[0][t] = mfma16(a0, bs, acc[0][t]);
                      acc[0][t] = mfma16(g0, bn, acc[0][t]); }
            if (v1) { acc[1][t] = mfma16(a1, bs, acc[1][t]);
                      acc[1][t] = mfma16(g1, bn, acc[1][t]); }
        }
    }

    #pragma unroll
    for (int r = 0; r < 2; ++r) {
        const bool vr = r ? v1 : v0;
        if (vr) {
            const int rT = rbase + r * 16 + 4 * lh;
            #pragma unroll
            for (int t = 0; t < NT; ++t) {
                const int c = t * 16 + lr;
                const float bb = bias[c];
                #pragma unroll
                for (int g = 0; g < 4; ++g) {
                    const int row = rT + g;
                    float v = acc[r][t][g] + bb;
                    outh[(size_t)row * N + c] = (f16)fmaxf(v, 0.f);
                }
            }
        }
    }
}

// ---------------- host orchestration ----------------------------------------
static inline int cdiv_i(long long a, int b) { return (int)((a + b - 1) / b); }

template<int F>
static void launch_gather(const f16* xh, const int* col, const int* rowptr,
                          const float* sbuf, const f16* hcopyh,
                          f16* outh, float* outf, int M, int ldout, int relu,
                          hipStream_t stream) {
    hipLaunchKernelGGL((gather_fused_h<F>), dim3(cdiv_i(M, TB / 64)), dim3(TB), 0, stream,
                       (const uint2*)xh, col, rowptr, sbuf, hcopyh, outh, outf,
                       M, ldout, relu);
}

extern "C" void kernel_launch(void* const* d_in, const int* in_sizes, int n_in,
                              void* d_out, int out_size, void* d_ws, size_t ws_size,
                              hipStream_t stream) {
    const float* in_feat = (const float*)d_in[0];
    const void* src = d_in[1];
    const void* dst = d_in[2];
    const float* Ws1 = (const float*)d_in[3];  const float* Wn1 = (const float*)d_in[4];  const float* b1 = (const float*)d_in[5];
    const float* Ws2 = (const float*)d_in[6];  const float* Wn2 = (const float*)d_in[7];  const float* b2 = (const float*)d_in[8];
    const float* Ws3 = (const float*)d_in[9];  const float* Wn3 = (const float*)d_in[10]; const float* b3 = (const float*)d_in[11];
    const float* Ws4 = (const float*)d_in[12]; const float* Wn4 = (const float*)d_in[13]; const float* b4 = (const float*)d_in[14];
    const float* Ws5 = (const float*)d_in[15]; const float* Wn5 = (const float*)d_in[16]; const float* b5 = (const float*)d_in[17];
    const float* Ws6 = (const float*)d_in[18]; const float* Wn6 = (const float*)d_in[19]; const float* b6 = (const float*)d_in[20];

    const int M  = in_sizes[0] / 64;   // 100000 nodes
    const int nE = in_sizes[1];        // 1600000 edges
    const int nBk = cdiv_i(M, 256);    // coarse buckets (391)
    const int EC  = cdiv_i(nE, NBLK_P);

    // workspace layout
    float* sbuf = (float*)d_ws;                   // M*64 f32 (S; aliased ebuf in build)
    f16* Yh   = (f16*)(sbuf + (size_t)M * 64);    // M*64
    f16* P1h  = Yh + (size_t)M * 64;              // M*128
    f16* P2h  = P1h + (size_t)M * 128;            // M*64
    f16* P3h  = P2h + (size_t)M * 64;             // M*32
    f16* aggh = P3h + (size_t)M * 32;             // M*64
    f16* xh   = aggh + (size_t)M * 64;            // M*64
    int* rowptr = (int*)(xh + (size_t)M * 64);    // M+1
    int* col    = rowptr + (M + 1);               // nE
    int* T      = col + nE;                       // NBK
    int* Bbase  = T + NBK;                        // NBK
    int* flag   = Bbase + NBK;                    // 1
    int* H      = flag + 1;                       // NBLK_P * NBK
    int2* ebuf  = (int2*)sbuf;                    // nE int2 (build only)

    // ---- CSR build (counting sort; no global atomics)
    hipLaunchKernelGGL(detect_idx_kernel, dim3(1), dim3(TB), 0, stream,
                       (const int*)src, (const int*)dst, nE, flag);
    hipLaunchKernelGGL(passA_kernel, dim3(NBLK_P), dim3(TB), 0, stream,
                       dst, flag, H, nE, EC, nBk);
    hipLaunchKernelGGL(colscan_kernel, dim3(cdiv_i(nBk, TB)), dim3(TB), 0, stream,
                       H, T, nBk);
    hipLaunchKernelGGL(bucket_scan_kernel, dim3(1), dim3(512), 0, stream, T, Bbase, nBk);
    hipLaunchKernelGGL(passB_kernel, dim3(NBLK_P), dim3(TB), 0, stream,
                       src, dst, flag, H, Bbase, ebuf, nE, EC, nBk);
    hipLaunchKernelGGL(bucket_build_kernel, dim3(nBk), dim3(TB), 0, stream,
                       ebuf, Bbase, rowptr, col, M, nBk, nE);

    // fp16 copy of in_feat
    hipLaunchKernelGGL(tofp16_kernel, dim3(cdiv_i((long long)M * 16, TB)), dim3(TB), 0, stream,
                       (const float4*)in_feat, (uint2*)xh, M * 16);

    const int mblocks = cdiv_i(M, 128);   // MFMA GEMM grid (128 rows/block)

    // ---- layer 1: 64 -> 128, relu: h1 = relu(x@Ws1 + mean(x)@Wn1 + b1)
    launch_gather<64>(xh, col, rowptr, nullptr, nullptr, aggh, nullptr, M, 64, 0, stream);
    hipLaunchKernelGGL((gemm_mfma_dualin<64, 128>), dim3(mblocks), dim3(TB), 0, stream,
                       xh, aggh, Ws1, Wn1, b1, P1h, M);

    // ---- layer 2: 128 -> 64, relu
    hipLaunchKernelGGL((gemm_mfma_dualout<128, 64>), dim3(mblocks), dim3(TB), 0, stream,
                       P1h, Wn2, Ws2, b2, Yh, sbuf, M);
    launch_gather<64>(Yh, col, rowptr, sbuf, nullptr, P2h, nullptr, M, 64, 1, stream);

    // ---- layer 3: 64 -> 32, relu
    hipLaunchKernelGGL((gemm_mfma_dualout<64, 32>), dim3(mblocks), dim3(TB), 0, stream,
                       P2h, Wn3, Ws3, b3, Yh, sbuf, M);
    launch_gather<32>(Yh, col, rowptr, sbuf, nullptr, P3h, nullptr, M, 32, 1, stream);

    // ---- layer 4: 32 -> 32, relu, concat h3 -> h4 (64 wide)
    hipLaunchKernelGGL((gemm_mfma_dualout<32, 32>), dim3(mblocks), dim3(TB), 0, stream,
                       P3h, Wn4, Ws4, b4, Yh, sbuf, M);
    launch_gather<32>(Yh, col, rowptr, sbuf, P3h, P2h, nullptr, M, 64, 1, stream);

    // ---- layer 5: 64 -> 64, relu, concat h4 -> h5 (128 wide)
    hipLaunchKernelGGL((gemm_mfma_dualout<64, 64>), dim3(mblocks), dim3(TB), 0, stream,
                       P2h, Wn5, Ws5, b5, Yh, sbuf, M);
    launch_gather<64>(Yh, col, rowptr, sbuf, P2h, P1h, nullptr, M, 128, 1, stream);

    // ---- layer 6: 128 -> 64, no relu, f32 out to d_out
    hipLaunchKernelGGL((gemm_mfma_dualout<128, 64>), dim3(mblocks), dim3(TB), 0, stream,
                       P1h, Wn6, Ws6, b6, Yh, sbuf, M);
    launch_gather<64>(Yh, col, rowptr, sbuf, nullptr, nullptr, (float*)d_out, M, 64, 0, stream);
}

// Round 13
// 465.612 us; speedup vs baseline: 1.0129x; 1.0129x over previous
//
#include <hip/hip_runtime.h>
#include <hip/hip_fp16.h>

#define TB 256
#define NBK 512     // bucket array capacity (actual buckets = cdiv(M,256) <= 512)
#define NBLK_P 256  // partition blocks (H-matrix rows)

typedef _Float16 f16;
typedef __attribute__((ext_vector_type(8))) _Float16 f16x8;
typedef __attribute__((ext_vector_type(4))) float f32x4;

__device__ __forceinline__ f32x4 mfma16(f16x8 a, f16x8 b, f32x4 c) {
    return __builtin_amdgcn_mfma_f32_16x16x32_f16(a, b, c, 0, 0, 0);
}

// ---------------- index-width detection (int32 vs int64 src/dst) -------------
__global__ void detect_idx_kernel(const int* __restrict__ s32, const int* __restrict__ d32,
                                  int nE, int* __restrict__ flag) {
    __shared__ int nz;
    if (threadIdx.x == 0) nz = 0;
    __syncthreads();
    int n = nE < 2048 ? nE : 2048;
    int local = 0;
    for (int i = threadIdx.x; i < n; i += blockDim.x) {
        if (s32[2 * i + 1] != 0 || d32[2 * i + 1] != 0) local = 1;
    }
    if (local) atomicOr(&nz, 1);
    __syncthreads();
    if (threadIdx.x == 0) *flag = (nz == 0) ? 1 : 0;   // 1 => indices are int64
}

__device__ __forceinline__ int load_idx(const void* p, int e, int is64) {
    return is64 ? (int)((const long long*)p)[e] : ((const int*)p)[e];
}

// ---------------- CSR build: contention-free counting sort -------------------
__global__ __launch_bounds__(TB) void passA_kernel(
        const void* __restrict__ dst, const int* __restrict__ flag,
        int* __restrict__ H, int nE, int EC, int nBk) {
    __shared__ int lh[NBK];
    for (int i = threadIdx.x; i < NBK; i += TB) lh[i] = 0;
    __syncthreads();
    const int is64 = *flag;
    const int lo = blockIdx.x * EC;
    const int hi = min(nE, lo + EC);
    for (int j = lo + threadIdx.x; j < hi; j += TB) {
        int d = load_idx(dst, j, is64);
        atomicAdd(&lh[d >> 8], 1);
    }
    __syncthreads();
    for (int i = threadIdx.x; i < nBk; i += TB) H[blockIdx.x * nBk + i] = lh[i];
}

__global__ __launch_bounds__(TB) void colscan_kernel(int* __restrict__ H,
                                                     int* __restrict__ T, int nBk) {
    int t = blockIdx.x * blockDim.x + threadIdx.x;
    if (t >= nBk) return;
    int run = 0;
    for (int b = 0; b < NBLK_P; ++b) {
        int v = H[b * nBk + t];
        H[b * nBk + t] = run;
        run += v;
    }
    T[t] = run;
}

__global__ __launch_bounds__(512) void bucket_scan_kernel(const int* __restrict__ hb,
                                                          int* __restrict__ bcur, int nBk) {
    __shared__ int sh[512];
    const int tid = threadIdx.x;
    int v = (tid < nBk) ? hb[tid] : 0;
    sh[tid] = v;
    __syncthreads();
    for (int off = 1; off < 512; off <<= 1) {
        int t = (tid >= off) ? sh[tid - off] : 0;
        __syncthreads();
        sh[tid] += t;
        __syncthreads();
    }
    if (tid < nBk) bcur[tid] = sh[tid] - v;   // exclusive
}

__global__ __launch_bounds__(TB) void passB_kernel(
        const void* __restrict__ src, const void* __restrict__ dst,
        const int* __restrict__ flag, const int* __restrict__ H,
        const int* __restrict__ Bbase, int2* __restrict__ ebuf,
        int nE, int EC, int nBk) {
    __shared__ int lbase[NBK];
    __shared__ int lcur[NBK];
    for (int i = threadIdx.x; i < nBk; i += TB) {
        lbase[i] = Bbase[i] + H[blockIdx.x * nBk + i];
        lcur[i] = 0;
    }
    __syncthreads();
    const int is64 = *flag;
    const int lo = blockIdx.x * EC;
    const int hi = min(nE, lo + EC);
    for (int j = lo + threadIdx.x; j < hi; j += TB) {
        int d = load_idx(dst, j, is64);
        int s = load_idx(src, j, is64);
        int bk = d >> 8;
        int p = lbase[bk] + atomicAdd(&lcur[bk], 1);
        ebuf[p] = make_int2(d, s);
    }
}

__global__ __launch_bounds__(TB) void bucket_build_kernel(
        const int2* __restrict__ ebuf, const int* __restrict__ Bbase,
        int* __restrict__ rowptr, int* __restrict__ col, int M, int nBk, int nE) {
    __shared__ int ldeg[256];
    __shared__ int wtot[4];
    const int bk = blockIdx.x;
    const int tid = threadIdx.x;
    const int node0 = bk << 8;
    const int lo = Bbase[bk];
    const int hi = (bk + 1 < nBk) ? Bbase[bk + 1] : nE;

    ldeg[tid] = 0;
    __syncthreads();
    for (int j = lo + tid; j < hi; j += TB)
        atomicAdd(&ldeg[ebuf[j].x & 255], 1);
    __syncthreads();

    const int lane = tid & 63, wv = tid >> 6;
    int v = ldeg[tid];
    int x = v;
    #pragma unroll
    for (int off = 1; off < 64; off <<= 1) {
        int y = __shfl_up(x, off);
        if (lane >= off) x += y;
    }
    if (lane == 63) wtot[wv] = x;
    __syncthreads();
    int wbase = 0;
    #pragma unroll
    for (int w = 0; w < 4; ++w) if (w < wv) wbase += wtot[w];
    const int excl = lo + wbase + (x - v);

    const int node = node0 + tid;
    if (node < M) rowptr[node] = excl;
    if (bk == 0 && tid == 0) rowptr[M] = nE;
    __syncthreads();
    ldeg[tid] = excl;   // becomes cursor
    __syncthreads();
    for (int j = lo + tid; j < hi; j += TB) {
        int2 e = ebuf[j];
        int pos = atomicAdd(&ldeg[e.x & 255], 1);
        col[pos] = e.y;
    }
}

// ---------------- f32 -> fp16 conversion -------------------------------------
__global__ void tofp16_kernel(const float4* __restrict__ in, uint2* __restrict__ out, int n4) {
    int t = blockIdx.x * blockDim.x + threadIdx.x;
    if (t >= n4) return;
    float4 v = in[t];
    __half2 a = __floats2half2_rn(v.x, v.y);
    __half2 b = __floats2half2_rn(v.z, v.w);
    out[t] = make_uint2(*(unsigned*)&a, *(unsigned*)&b);
}

// ---------------- fused gather (all-fp16 streams) ----------------------------
// out = relu?(sbuf + mean_nbr(x)); sbuf fp16; out fp16 (+concat) or f32 d_out
template<int F>
__global__ __launch_bounds__(TB) void gather_fused_h(
        const uint2* __restrict__ xh, const int* __restrict__ col,
        const int* __restrict__ rowptr, const f16* __restrict__ sbufh,
        const f16* __restrict__ hcopyh, f16* __restrict__ outh,
        float* __restrict__ outf, int M, int ldout, int doRelu) {
    constexpr int C4 = F / 4;      // 8-byte chunks per row: 16 (F=64) or 8 (F=32)
    constexpr int ES = 64 / C4;    // edge slices per wave
    const int wave = threadIdx.x >> 6;
    const int lane = threadIdx.x & 63;
    const int node = blockIdx.x * (TB / 64) + wave;
    if (node >= M) return;
    const int c4 = lane & (C4 - 1);
    const int es = lane >> (F == 64 ? 4 : 3);

    const int s = rowptr[node], e = rowptr[node + 1];
    __half2 h0 = __floats2half2_rn(0.f, 0.f);
    __half2 h1 = h0;
    int j = s + es;
    for (; j + 3 * ES < e; j += 4 * ES) {
        int cs0 = col[j];
        int cs1 = col[j + ES];
        int cs2 = col[j + 2 * ES];
        int cs3 = col[j + 3 * ES];
        uint2 u0 = xh[(size_t)cs0 * C4 + c4];
        uint2 u1 = xh[(size_t)cs1 * C4 + c4];
        uint2 u2 = xh[(size_t)cs2 * C4 + c4];
        uint2 u3 = xh[(size_t)cs3 * C4 + c4];
        h0 = __hadd2(h0, *(__half2*)&u0.x); h1 = __hadd2(h1, *(__half2*)&u0.y);
        h0 = __hadd2(h0, *(__half2*)&u1.x); h1 = __hadd2(h1, *(__half2*)&u1.y);
        h0 = __hadd2(h0, *(__half2*)&u2.x); h1 = __hadd2(h1, *(__half2*)&u2.y);
        h0 = __hadd2(h0, *(__half2*)&u3.x); h1 = __hadd2(h1, *(__half2*)&u3.y);
    }
    for (; j < e; j += ES) {
        int cs = col[j];
        uint2 u = xh[(size_t)cs * C4 + c4];
        h0 = __hadd2(h0, *(__half2*)&u.x);
        h1 = __hadd2(h1, *(__half2*)&u.y);
    }
    float2 f0 = __half22float2(h0);
    float2 f1 = __half22float2(h1);
    float ax = f0.x, ay = f0.y, az = f1.x, aw = f1.y;
    #pragma unroll
    for (int d = C4; d < 64; d <<= 1) {
        ax += __shfl_xor(ax, d);
        ay += __shfl_xor(ay, d);
        az += __shfl_xor(az, d);
        aw += __shfl_xor(aw, d);
    }
    if (es == 0) {
        const float inv = 1.0f / fmaxf((float)(e - s), 1.0f);
        float4 v = make_float4(ax * inv, ay * inv, az * inv, aw * inv);
        if (sbufh) {
            uint2 su = *(const uint2*)(sbufh + (size_t)node * F + 4 * c4);
            float2 s0 = __half22float2(*(__half2*)&su.x);
            float2 s1 = __half22float2(*(__half2*)&su.y);
            v.x += s0.x; v.y += s0.y; v.z += s1.x; v.w += s1.y;
        }
        if (doRelu) {
            v.x = fmaxf(v.x, 0.f); v.y = fmaxf(v.y, 0.f);
            v.z = fmaxf(v.z, 0.f); v.w = fmaxf(v.w, 0.f);
        }
        if (outh) {
            __half2 p0 = __floats2half2_rn(v.x, v.y);
            __half2 p1 = __floats2half2_rn(v.z, v.w);
            *(uint2*)(outh + (size_t)node * ldout + 4 * c4) =
                make_uint2(*(unsigned*)&p0, *(unsigned*)&p1);
            if (hcopyh) {   // concat: copy prev h (fp16) into upper half
                uint2 hv = *(const uint2*)(hcopyh + (size_t)node * F + 4 * c4);
                *(uint2*)(outh + (size_t)node * ldout + F + 4 * c4) = hv;
            }
        }
        if (outf)
            *(float4*)(outf + (size_t)node * ldout + 4 * c4) = v;
    }
}

// ---------------- MFMA dual-OUTPUT GEMM: Yh = fp16(A@Wn); Sh = fp16(A@Ws+b) --
template<int K, int N>
__global__ __launch_bounds__(TB) void gemm_mfma_dualout(
        const f16* __restrict__ Ah, const float* __restrict__ Wn,
        const float* __restrict__ Ws, const float* __restrict__ bias,
        f16* __restrict__ Yh, f16* __restrict__ Sh, int M) {
    constexpr int KP = K + 8;      // padded k-stride (halves) -> conflict-free
    constexpr int NT = N / 16;     // n tiles per wave
    constexpr int KS = K / 32;     // k steps
    __shared__ f16 lwn[N * KP];
    __shared__ f16 lws[N * KP];
    const int tid = threadIdx.x;
    for (int idx = tid; idx < K * N; idx += TB) {
        int k = idx / N, n = idx - k * N;
        lwn[n * KP + k] = (f16)Wn[idx];
        lws[n * KP + k] = (f16)Ws[idx];
    }
    __syncthreads();

    const int lane = tid & 63;
    const int lr = lane & 15, lh = lane >> 4;
    const int rbase = blockIdx.x * 128 + (tid >> 6) * 32;
    const bool v0 = rbase < M, v1 = rbase + 16 < M;   // M % 16 == 0

    f32x4 accY[2][NT], accS[2][NT];
    const f32x4 z = {0.f, 0.f, 0.f, 0.f};
    #pragma unroll
    for (int r = 0; r < 2; ++r)
        #pragma unroll
        for (int t = 0; t < NT; ++t) { accY[r][t] = z; accS[r][t] = z; }

    for (int ks = 0; ks < KS; ++ks) {
        const int kb = ks * 32 + lh * 8;
        f16x8 a0 = {}, a1 = {};
        if (v0) a0 = *(const f16x8*)(Ah + (size_t)(rbase + lr) * K + kb);
        if (v1) a1 = *(const f16x8*)(Ah + (size_t)(rbase + 16 + lr) * K + kb);
        #pragma unroll
        for (int t = 0; t < NT; ++t) {
            f16x8 bn = *(const f16x8*)(&lwn[(t * 16 + lr) * KP + kb]);
            f16x8 bs = *(const f16x8*)(&lws[(t * 16 + lr) * KP + kb]);
            if (v0) { accY[0][t] = mfma16(a0, bn, accY[0][t]);
                      accS[0][t] = mfma16(a0, bs, accS[0][t]); }
            if (v1) { accY[1][t] = mfma16(a1, bn, accY[1][t]);
                      accS[1][t] = mfma16(a1, bs, accS[1][t]); }
        }
    }

    #pragma unroll
    for (int r = 0; r < 2; ++r) {
        const bool vr = r ? v1 : v0;
        if (vr) {
            const int rT = rbase + r * 16 + 4 * lh;   // D: row=(lane>>4)*4+reg
            #pragma unroll
            for (int t = 0; t < NT; ++t) {
                const int c = t * 16 + lr;            // D: col=lane&15
                const float bb = bias[c];
                #pragma unroll
                for (int g = 0; g < 4; ++g) {
                    const int row = rT + g;
                    Sh[(size_t)row * N + c] = (f16)(accS[r][t][g] + bb);
                    Yh[(size_t)row * N + c] = (f16)accY[r][t][g];
                }
            }
        }
    }
}

// ---------------- MFMA dual-INPUT GEMM (layer 1): relu(A@Ws + A2@Wn + b) -----
template<int K, int N>
__global__ __launch_bounds__(TB) void gemm_mfma_dualin(
        const f16* __restrict__ Ah, const f16* __restrict__ A2h,
        const float* __restrict__ Ws, const float* __restrict__ Wn,
        const float* __restrict__ bias, f16* __restrict__ outh, int M) {
    constexpr int KP = K + 8;
    constexpr int NT = N / 16;
    constexpr int KS = K / 32;
    __shared__ f16 lws[N * KP];
    __shared__ f16 lwn[N * KP];
    const int tid = threadIdx.x;
    for (int idx = tid; idx < K * N; idx += TB) {
        int k = idx / N, n = idx - k * N;
        lws[n * KP + k] = (f16)Ws[idx];
        lwn[n * KP + k] = (f16)Wn[idx];
    }
    __syncthreads();

    const int lane = tid & 63;
    const int lr = lane & 15, lh = lane >> 4;
    const int rbase = blockIdx.x * 128 + (tid >> 6) * 32;
    const bool v0 = rbase < M, v1 = rbase + 16 < M;

    f32x4 acc[2][NT];
    const f32x4 z = {0.f, 0.f, 0.f, 0.f};
    #pragma unroll
    for (int r = 0; r < 2; ++r)
        #pragma unroll
        for (int t = 0; t < NT; ++t) acc[r][t] = z;

    for (int ks = 0; ks < KS; ++ks) {
        const int kb = ks * 32 + lh * 8;
        f16x8 a0 = {}, a1 = {}, g0 = {}, g1 = {};
        if (v0) { a0 = *(const f16x8*)(Ah  + (size_t)(rbase + lr) * K + kb);
                  g0 = *(const f16x8*)(A2h + (size_t)(rbase + lr) * K + kb); }
        if (v1) { a1 = *(const f16x8*)(Ah  + (size_t)(rbase + 16 + lr) * K + kb);
                  g1 = *(const f16x8*)(A2h + (size_t)(rbase + 16 + lr) * K + kb); }
        #pragma unroll
        for (int t = 0; t < NT; ++t) {
            f16x8 bs = *(const f16x8*)(&lws[(t * 16 + lr) * KP + kb]);
            f16x8 bn = *(const f16x8*)(&lwn[(t * 16 + lr) * KP + kb]);
            if (v0) { acc[0][t] = mfma16(a0, bs, acc[0][t]);
                      acc[0][t] = mfma16(g0, bn, acc[0][t]); }
            if (v1) { acc[1][t] = mfma16(a1, bs, acc[1][t]);
                      acc[1][t] = mfma16(g1, bn, acc[1][t]); }
        }
    }

    #pragma unroll
    for (int r = 0; r < 2; ++r) {
        const bool vr = r ? v1 : v0;
        if (vr) {
            const int rT = rbase + r * 16 + 4 * lh;
            #pragma unroll
            for (int t = 0; t < NT; ++t) {
                const int c = t * 16 + lr;
                const float bb = bias[c];
                #pragma unroll
                for (int g = 0; g < 4; ++g) {
                    const int row = rT + g;
                    float v = acc[r][t][g] + bb;
                    outh[(size_t)row * N + c] = (f16)fmaxf(v, 0.f);
                }
            }
        }
    }
}

// ---------------- host orchestration ----------------------------------------
static inline int cdiv_i(long long a, int b) { return (int)((a + b - 1) / b); }

template<int F>
static void launch_gather(const f16* xh, const int* col, const int* rowptr,
                          const f16* sbufh, const f16* hcopyh,
                          f16* outh, float* outf, int M, int ldout, int relu,
                          hipStream_t stream) {
    hipLaunchKernelGGL((gather_fused_h<F>), dim3(cdiv_i(M, TB / 64)), dim3(TB), 0, stream,
                       (const uint2*)xh, col, rowptr, sbufh, hcopyh, outh, outf,
                       M, ldout, relu);
}

extern "C" void kernel_launch(void* const* d_in, const int* in_sizes, int n_in,
                              void* d_out, int out_size, void* d_ws, size_t ws_size,
                              hipStream_t stream) {
    const float* in_feat = (const float*)d_in[0];
    const void* src = d_in[1];
    const void* dst = d_in[2];
    const float* Ws1 = (const float*)d_in[3];  const float* Wn1 = (const float*)d_in[4];  const float* b1 = (const float*)d_in[5];
    const float* Ws2 = (const float*)d_in[6];  const float* Wn2 = (const float*)d_in[7];  const float* b2 = (const float*)d_in[8];
    const float* Ws3 = (const float*)d_in[9];  const float* Wn3 = (const float*)d_in[10]; const float* b3 = (const float*)d_in[11];
    const float* Ws4 = (const float*)d_in[12]; const float* Wn4 = (const float*)d_in[13]; const float* b4 = (const float*)d_in[14];
    const float* Ws5 = (const float*)d_in[15]; const float* Wn5 = (const float*)d_in[16]; const float* b5 = (const float*)d_in[17];
    const float* Ws6 = (const float*)d_in[18]; const float* Wn6 = (const float*)d_in[19]; const float* b6 = (const float*)d_in[20];

    const int M  = in_sizes[0] / 64;   // 100000 nodes
    const int nE = in_sizes[1];        // 1600000 edges
    const int nBk = cdiv_i(M, 256);    // coarse buckets (391)
    const int EC  = cdiv_i(nE, NBLK_P);

    // workspace layout (all-fp16 activations; Sh aliased by ebuf during build)
    f16* Sh   = (f16*)d_ws;                       // M*64 (12.8 MB, == nE int2)
    f16* Yh   = Sh + (size_t)M * 64;              // M*64
    f16* P1h  = Yh + (size_t)M * 64;              // M*128
    f16* P2h  = P1h + (size_t)M * 128;            // M*64
    f16* P3h  = P2h + (size_t)M * 64;             // M*32
    f16* aggh = P3h + (size_t)M * 32;             // M*64
    f16* xh   = aggh + (size_t)M * 64;            // M*64
    int* rowptr = (int*)(xh + (size_t)M * 64);    // M+1
    int* col    = rowptr + (M + 1);               // nE
    int* T      = col + nE;                       // NBK
    int* Bbase  = T + NBK;                        // NBK
    int* flag   = Bbase + NBK;                    // 1
    int* H      = flag + 1;                       // NBLK_P * NBK
    int2* ebuf  = (int2*)Sh;                      // nE int2 (build only)

    // ---- CSR build (counting sort; no global atomics)
    hipLaunchKernelGGL(detect_idx_kernel, dim3(1), dim3(TB), 0, stream,
                       (const int*)src, (const int*)dst, nE, flag);
    hipLaunchKernelGGL(passA_kernel, dim3(NBLK_P), dim3(TB), 0, stream,
                       dst, flag, H, nE, EC, nBk);
    hipLaunchKernelGGL(colscan_kernel, dim3(cdiv_i(nBk, TB)), dim3(TB), 0, stream,
                       H, T, nBk);
    hipLaunchKernelGGL(bucket_scan_kernel, dim3(1), dim3(512), 0, stream, T, Bbase, nBk);
    hipLaunchKernelGGL(passB_kernel, dim3(NBLK_P), dim3(TB), 0, stream,
                       src, dst, flag, H, Bbase, ebuf, nE, EC, nBk);
    hipLaunchKernelGGL(bucket_build_kernel, dim3(nBk), dim3(TB), 0, stream,
                       ebuf, Bbase, rowptr, col, M, nBk, nE);

    // fp16 copy of in_feat
    hipLaunchKernelGGL(tofp16_kernel, dim3(cdiv_i((long long)M * 16, TB)), dim3(TB), 0, stream,
                       (const float4*)in_feat, (uint2*)xh, M * 16);

    const int mblocks = cdiv_i(M, 128);   // MFMA GEMM grid (128 rows/block)

    // ---- layer 1: 64 -> 128, relu: h1 = relu(x@Ws1 + mean(x)@Wn1 + b1)
    launch_gather<64>(xh, col, rowptr, nullptr, nullptr, aggh, nullptr, M, 64, 0, stream);
    hipLaunchKernelGGL((gemm_mfma_dualin<64, 128>), dim3(mblocks), dim3(TB), 0, stream,
                       xh, aggh, Ws1, Wn1, b1, P1h, M);

    // ---- layer 2: 128 -> 64, relu
    hipLaunchKernelGGL((gemm_mfma_dualout<128, 64>), dim3(mblocks), dim3(TB), 0, stream,
                       P1h, Wn2, Ws2, b2, Yh, Sh, M);
    launch_gather<64>(Yh, col, rowptr, Sh, nullptr, P2h, nullptr, M, 64, 1, stream);

    // ---- layer 3: 64 -> 32, relu
    hipLaunchKernelGGL((gemm_mfma_dualout<64, 32>), dim3(mblocks), dim3(TB), 0, stream,
                       P2h, Wn3, Ws3, b3, Yh, Sh, M);
    launch_gather<32>(Yh, col, rowptr, Sh, nullptr, P3h, nullptr, M, 32, 1, stream);

    // ---- layer 4: 32 -> 32, relu, concat h3 -> h4 (64 wide)
    hipLaunchKernelGGL((gemm_mfma_dualout<32, 32>), dim3(mblocks), dim3(TB), 0, stream,
                       P3h, Wn4, Ws4, b4, Yh, Sh, M);
    launch_gather<32>(Yh, col, rowptr, Sh, P3h, P2h, nullptr, M, 64, 1, stream);

    // ---- layer 5: 64 -> 64, relu, concat h4 -> h5 (128 wide)
    hipLaunchKernelGGL((gemm_mfma_dualout<64, 64>), dim3(mblocks), dim3(TB), 0, stream,
                       P2h, Wn5, Ws5, b5, Yh, Sh, M);
    launch_gather<64>(Yh, col, rowptr, Sh, P2h, P1h, nullptr, M, 128, 1, stream);

    // ---- layer 6: 128 -> 64, no relu, f32 out to d_out
    hipLaunchKernelGGL((gemm_mfma_dualout<128, 64>), dim3(mblocks), dim3(TB), 0, stream,
                       P1h, Wn6, Ws6, b6, Yh, Sh, M);
    launch_gather<64>(Yh, col, rowptr, Sh, nullptr, nullptr, (float*)d_out, M, 64, 0, stream);
}